// Round 2
// baseline (543.627 us; speedup 1.0000x reference)
//
#include <hip/hip_runtime.h>
#include <hip/hip_bf16.h>

// Problem constants (B=1)
constexpr int N_TOK = 2048;
constexpr int DIMM  = 1024;
constexpr int NH    = 16;
constexpr int HD    = 64;   // head dim D
constexpr int FM    = 64;   // num features M
constexpr int NC    = 32;   // chunks
constexpr int CS    = 64;   // chunk size

// C[n][m] = sum_k A[n][k] * B[m][k]  (NT GEMM; A:[Nrow,K] f32, B:[Mo,K] f32)
// Block tile 64(rows) x 128(cols), BK=16, 256 threads, 4x8 micro-tile.
template<int BIAS>
__global__ __launch_bounds__(256) void gemm_nt(
    const float* __restrict__ A, const float* __restrict__ B,
    const float* __restrict__ bias, float* __restrict__ C,
    int K, int Mo)
{
  __shared__ float As[16][64];
  __shared__ float Bs[16][132];
  const int tid = threadIdx.x;
  const int rowBase = blockIdx.y * 64;
  const int colBase = blockIdx.x * 128;
  const int tx = tid & 15, ty = tid >> 4;
  const int lrA = tid & 63, lkA = (tid >> 6) * 4;   // A: 64 rows x 16 k, 4 per thread
  const int lrB = tid >> 1, lkB = (tid & 1) * 8;    // B: 128 rows x 16 k, 8 per thread
  const float* Aptr = A + (size_t)(rowBase + lrA) * K + lkA;
  const float* Bptr = B + (size_t)(colBase + lrB) * K + lkB;

  float acc[4][8];
  #pragma unroll
  for (int u = 0; u < 4; u++)
    #pragma unroll
    for (int w = 0; w < 8; w++) acc[u][w] = 0.f;

  for (int kb = 0; kb < K; kb += 16) {
    float4 ra = *reinterpret_cast<const float4*>(Aptr + kb);
    float4 rb0 = *reinterpret_cast<const float4*>(Bptr + kb);
    float4 rb1 = *reinterpret_cast<const float4*>(Bptr + kb + 4);
    __syncthreads();
    As[lkA + 0][lrA] = ra.x; As[lkA + 1][lrA] = ra.y;
    As[lkA + 2][lrA] = ra.z; As[lkA + 3][lrA] = ra.w;
    Bs[lkB + 0][lrB] = rb0.x; Bs[lkB + 1][lrB] = rb0.y;
    Bs[lkB + 2][lrB] = rb0.z; Bs[lkB + 3][lrB] = rb0.w;
    Bs[lkB + 4][lrB] = rb1.x; Bs[lkB + 5][lrB] = rb1.y;
    Bs[lkB + 6][lrB] = rb1.z; Bs[lkB + 7][lrB] = rb1.w;
    __syncthreads();
    #pragma unroll
    for (int kk = 0; kk < 16; kk++) {
      float a[4], b[8];
      #pragma unroll
      for (int u = 0; u < 4; u++) a[u] = As[kk][ty * 4 + u];
      #pragma unroll
      for (int w = 0; w < 8; w++) b[w] = Bs[kk][tx * 8 + w];
      #pragma unroll
      for (int u = 0; u < 4; u++)
        #pragma unroll
        for (int w = 0; w < 8; w++) acc[u][w] += a[u] * b[w];
    }
  }

  #pragma unroll
  for (int u = 0; u < 4; u++) {
    int r = rowBase + ty * 4 + u;
    float* cp = C + (size_t)r * Mo + colBase + tx * 8;
    #pragma unroll
    for (int w = 0; w < 8; w++) {
      float v = acc[u][w];
      if (BIAS) v += bias[colBase + tx * 8 + w];
      cp[w] = v;
    }
  }
}

// phi[h][n][m] = exp(q[n,h,:].omega[m,:] - 0.5*||q[n,h,:]||^2) / 8
__global__ __launch_bounds__(64) void phi_kernel(
    const float* __restrict__ qf, const float* __restrict__ kf,
    const float* __restrict__ omega,
    float* __restrict__ phiq, float* __restrict__ phik)
{
  const int n = blockIdx.x, h = blockIdx.y;
  const int m = threadIdx.x;  // 0..63
  __shared__ float qs[64], ks[64];
  float qv = qf[(size_t)n * DIMM + h * HD + m];
  float kv = kf[(size_t)n * DIMM + h * HD + m];
  qs[m] = qv; ks[m] = kv;
  float nq = qv * qv, nk = kv * kv;
  #pragma unroll
  for (int off = 32; off > 0; off >>= 1) {
    nq += __shfl_xor(nq, off);
    nk += __shfl_xor(nk, off);
  }
  __syncthreads();
  float pq = 0.f, pk = 0.f;
  const float4* om = reinterpret_cast<const float4*>(omega + (size_t)m * FM);
  #pragma unroll
  for (int d4 = 0; d4 < 16; d4++) {
    float4 f = om[d4];
    pq += qs[d4 * 4 + 0] * f.x + qs[d4 * 4 + 1] * f.y
        + qs[d4 * 4 + 2] * f.z + qs[d4 * 4 + 3] * f.w;
    pk += ks[d4 * 4 + 0] * f.x + ks[d4 * 4 + 1] * f.y
        + ks[d4 * 4 + 2] * f.z + ks[d4 * 4 + 3] * f.w;
  }
  size_t o = ((size_t)h * N_TOK + n) * FM + m;
  float aq = fminf(pq - 0.5f * nq, 80.f);
  float ak = fminf(pk - 0.5f * nk, 80.f);
  phiq[o] = __expf(aq) * 0.125f;
  phik[o] = __expf(ak) * 0.125f;
}

// Per-chunk sums: ckv[h][c][m][d] = sum_{j in chunk} phik[h][cj][m]*v[cj][h,d]
__global__ __launch_bounds__(256) void chunk_sum(
    const float* __restrict__ phik, const float* __restrict__ vf,
    float* __restrict__ ckv, float* __restrict__ ck)
{
  const int c = blockIdx.x, h = blockIdx.y;
  __shared__ float sPk[64][65];
  __shared__ float sV[64][65];
  const int tid = threadIdx.x;
  for (int t = tid; t < 4096; t += 256) {
    int j = t >> 6, e = t & 63;
    sPk[j][e] = phik[((size_t)h * N_TOK + c * CS + j) * FM + e];
    sV[j][e]  = vf[(size_t)(c * CS + j) * DIMM + h * HD + e];
  }
  __syncthreads();
  const int tx = tid & 15, ty = tid >> 4;
  const int m0 = ty * 4, d0 = tx * 4;
  float acc[4][4] = {};
  for (int j = 0; j < 64; j++) {
    float p[4], v[4];
    #pragma unroll
    for (int u = 0; u < 4; u++) { p[u] = sPk[j][m0 + u]; v[u] = sV[j][d0 + u]; }
    #pragma unroll
    for (int u = 0; u < 4; u++)
      #pragma unroll
      for (int w = 0; w < 4; w++) acc[u][w] += p[u] * v[w];
  }
  float* dst = ckv + ((size_t)h * NC + c) * FM * HD;
  #pragma unroll
  for (int u = 0; u < 4; u++)
    #pragma unroll
    for (int w = 0; w < 4; w++) dst[(m0 + u) * HD + d0 + w] = acc[u][w];
  if (tid < 64) {
    float s = 0.f;
    for (int j = 0; j < 64; j++) s += sPk[j][tid];
    ck[((size_t)h * NC + c) * FM + tid] = s;
  }
}

// In-place exclusive prefix over chunks. grid (NH, 16): each y-slice owns 256 cells.
__global__ __launch_bounds__(256) void prefix_chunks(
    float* __restrict__ ckv, float* __restrict__ ck)
{
  const int h = blockIdx.x, g = blockIdx.y;
  const int cell = g * 256 + threadIdx.x;
  float run = 0.f;
  for (int c = 0; c < NC; c++) {
    size_t idx = ((size_t)h * NC + c) * 4096 + cell;
    float v = ckv[idx]; ckv[idx] = run; run += v;
  }
  if (g == 0 && threadIdx.x < 64) {
    float r2 = 0.f;
    for (int c = 0; c < NC; c++) {
      size_t idx = ((size_t)h * NC + c) * FM + threadIdx.x;
      float v = ck[idx]; ck[idx] = r2; r2 += v;
    }
  }
}

// Per-chunk causal attention: intra-chunk masked A @ V plus carry-in state.
__global__ __launch_bounds__(256) void attn_chunk(
    const float* __restrict__ phiq, const float* __restrict__ phik,
    const float* __restrict__ vf, const float* __restrict__ ckv,
    const float* __restrict__ ck, float* __restrict__ attn_out)
{
  const int c = blockIdx.x, h = blockIdx.y;
  __shared__ float sPq[64][65];
  __shared__ float sPk[64][65];   // reused as masked A after phase 1
  __shared__ float sV[64][65];
  __shared__ float sS[64][65];
  __shared__ float sKc[64];
  __shared__ float sDen[64];
  const int tid = threadIdx.x;
  const float* ckv_base = ckv + ((size_t)h * NC + c) * 4096;
  for (int t = tid; t < 4096; t += 256) {
    int i = t >> 6, e = t & 63;
    sPq[i][e] = phiq[((size_t)h * N_TOK + c * CS + i) * FM + e];
    sPk[i][e] = phik[((size_t)h * N_TOK + c * CS + i) * FM + e];
    sV[i][e]  = vf[(size_t)(c * CS + i) * DIMM + h * HD + e];
    sS[i][e]  = ckv_base[t];
  }
  if (tid < 64) sKc[tid] = ck[((size_t)h * NC + c) * FM + tid];
  __syncthreads();

  const int tx = tid & 15, ty = tid >> 4;
  const int i0 = ty * 4, j0 = tx * 4;

  // Phase 1: A[i][j] = phi_q[i] . phi_k[j]
  float accA[4][4] = {};
  for (int m = 0; m < 64; m++) {
    float a[4], b[4];
    #pragma unroll
    for (int u = 0; u < 4; u++) { a[u] = sPq[i0 + u][m]; b[u] = sPk[j0 + u][m]; }
    #pragma unroll
    for (int u = 0; u < 4; u++)
      #pragma unroll
      for (int w = 0; w < 4; w++) accA[u][w] += a[u] * b[w];
  }
  __syncthreads();  // everyone done reading sPk
  #pragma unroll
  for (int u = 0; u < 4; u++)
    #pragma unroll
    for (int w = 0; w < 4; w++)
      sPk[i0 + u][j0 + w] = (j0 + w <= i0 + u) ? accA[u][w] : 0.f;  // causal mask
  __syncthreads();

  // Phase 2: denominators
  if (tid < 64) {
    float den = 0.f;
    for (int m = 0; m < 64; m++) den += sPq[tid][m] * sKc[m];
    for (int j = 0; j < 64; j++) den += sPk[tid][j];
    sDen[tid] = 1.f / (den + 1e-6f);
  }
  __syncthreads();

  // Phase 3: out[i][d] = A_masked @ V + phi_q @ S_prefix, scaled by 1/den
  float accO[4][4] = {};
  for (int j = 0; j < 64; j++) {
    float a[4], v[4];
    #pragma unroll
    for (int u = 0; u < 4; u++) { a[u] = sPk[i0 + u][j]; v[u] = sV[j][j0 + u]; }
    #pragma unroll
    for (int u = 0; u < 4; u++)
      #pragma unroll
      for (int w = 0; w < 4; w++) accO[u][w] += a[u] * v[w];
  }
  for (int m = 0; m < 64; m++) {
    float a[4], s[4];
    #pragma unroll
    for (int u = 0; u < 4; u++) { a[u] = sPq[i0 + u][m]; s[u] = sS[m][j0 + u]; }
    #pragma unroll
    for (int u = 0; u < 4; u++)
      #pragma unroll
      for (int w = 0; w < 4; w++) accO[u][w] += a[u] * s[w];
  }
  #pragma unroll
  for (int u = 0; u < 4; u++) {
    int n = c * CS + i0 + u;
    float inv = sDen[i0 + u];
    float4 o4 = make_float4(accO[u][0] * inv, accO[u][1] * inv,
                            accO[u][2] * inv, accO[u][3] * inv);
    *reinterpret_cast<float4*>(attn_out + (size_t)n * DIMM + h * HD + j0) = o4;
  }
}

extern "C" void kernel_launch(void* const* d_in, const int* in_sizes, int n_in,
                              void* d_out, int out_size, void* d_ws, size_t ws_size,
                              hipStream_t stream) {
  (void)in_sizes; (void)n_in; (void)out_size; (void)ws_size;
  const float* x     = (const float*)d_in[0];
  const float* omega = (const float*)d_in[1];
  const float* wq    = (const float*)d_in[2];
  const float* wk    = (const float*)d_in[3];
  const float* wv    = (const float*)d_in[4];
  const float* wo    = (const float*)d_in[5];
  const float* bo    = (const float*)d_in[6];
  float* out = (float*)d_out;

  // Workspace layout (~48 MB); attn reuses qf (dead after phi_kernel).
  float* qf   = (float*)d_ws;                       // [N,1024]
  float* kf   = qf   + (size_t)N_TOK * DIMM;        // [N,1024]
  float* vf   = kf   + (size_t)N_TOK * DIMM;        // [N,1024]
  float* phiq = vf   + (size_t)N_TOK * DIMM;        // [H,N,64]
  float* phik = phiq + (size_t)NH * N_TOK * FM;     // [H,N,64]
  float* ckv  = phik + (size_t)NH * N_TOK * FM;     // [H,NC,64,64]
  float* ck   = ckv  + (size_t)NH * NC * FM * HD;   // [H,NC,64]
  float* attn = qf;                                 // reuse

  dim3 gGemm(DIMM / 128, N_TOK / 64);
  gemm_nt<0><<<gGemm, 256, 0, stream>>>(x, wq, nullptr, qf, DIMM, DIMM);
  gemm_nt<0><<<gGemm, 256, 0, stream>>>(x, wk, nullptr, kf, DIMM, DIMM);
  gemm_nt<0><<<gGemm, 256, 0, stream>>>(x, wv, nullptr, vf, DIMM, DIMM);

  phi_kernel<<<dim3(N_TOK, NH), 64, 0, stream>>>(qf, kf, omega, phiq, phik);

  chunk_sum<<<dim3(NC, NH), 256, 0, stream>>>(phik, vf, ckv, ck);
  prefix_chunks<<<dim3(NH, 16), 256, 0, stream>>>(ckv, ck);
  attn_chunk<<<dim3(NC, NH), 256, 0, stream>>>(phiq, phik, vf, ckv, ck, attn);

  gemm_nt<1><<<gGemm, 256, 0, stream>>>(attn, wo, bo, out, DIMM, DIMM);
}

// Round 3
// 262.896 us; speedup vs baseline: 2.0678x; 2.0678x over previous
//
#include <hip/hip_runtime.h>
#include <hip/hip_bf16.h>

typedef __hip_bfloat16 bf16;
typedef __attribute__((ext_vector_type(8))) short bf16x8;
typedef __attribute__((ext_vector_type(4))) float f32x4;

constexpr int N_TOK = 2048;
constexpr int DIMM  = 1024;
constexpr int NH    = 16;
constexpr int HD    = 64;
constexpr int FM    = 64;
constexpr int NC    = 32;
constexpr int CS    = 64;

__device__ __forceinline__ float b2f(bf16 v) { return __bfloat162float(v); }
__device__ __forceinline__ unsigned short f2bfu(float v) {
  bf16 h = __float2bfloat16(v);
  return *reinterpret_cast<unsigned short*>(&h);
}

// async global->LDS, 16B per lane. LDS dest = wave-uniform base + lane*16B.
__device__ __forceinline__ void gl_lds16(const bf16* g, short* l) {
  __builtin_amdgcn_global_load_lds(
      (const __attribute__((address_space(1))) void*)g,
      (__attribute__((address_space(3))) void*)l, 16, 0, 0);
}

// fp32 -> bf16 hi/lo split (vectorized by 4)
__global__ __launch_bounds__(256) void cvt_split(
    const float4* __restrict__ src, bf16* __restrict__ hi, bf16* __restrict__ lo, int n4)
{
  int i = blockIdx.x * 256 + threadIdx.x;
  if (i >= n4) return;
  float4 v = src[i];
  float f[4] = {v.x, v.y, v.z, v.w};
  unsigned short h[4], l[4];
  #pragma unroll
  for (int j = 0; j < 4; j++) {
    bf16 hb = __float2bfloat16(f[j]);
    h[j] = *reinterpret_cast<unsigned short*>(&hb);
    l[j] = f2bfu(f[j] - b2f(hb));
  }
  uint2 ph, pl;
  ph.x = (unsigned)h[0] | ((unsigned)h[1] << 16);
  ph.y = (unsigned)h[2] | ((unsigned)h[3] << 16);
  pl.x = (unsigned)l[0] | ((unsigned)l[1] << 16);
  pl.y = (unsigned)l[2] | ((unsigned)l[3] << 16);
  reinterpret_cast<uint2*>(hi)[i] = ph;
  reinterpret_cast<uint2*>(lo)[i] = pl;
}

__global__ __launch_bounds__(256) void cvt_bf(
    const float4* __restrict__ src, bf16* __restrict__ dst, int n4)
{
  int i = blockIdx.x * 256 + threadIdx.x;
  if (i >= n4) return;
  float4 v = src[i];
  uint2 p;
  p.x = (unsigned)f2bfu(v.x) | ((unsigned)f2bfu(v.y) << 16);
  p.y = (unsigned)f2bfu(v.z) | ((unsigned)f2bfu(v.w) << 16);
  reinterpret_cast<uint2*>(dst)[i] = p;
}

// Split-bf16 NT GEMM: C[n][m] = sum_k (Ah+Al)[n][k]*(Bh+Bl)[m][k] (minus lo*lo).
// 128x128 tile, BK=32, 256 threads = 4 waves (2x2 of 64x64).
// Cols < 2048 -> fp32 into Cq (stride 2048); cols >= 2048 -> bf16 into Cv (stride 1024).
__global__ __launch_bounds__(256) void gemm_split_qkv(
    const bf16* __restrict__ Ah, const bf16* __restrict__ Al,
    const bf16* __restrict__ Bh, const bf16* __restrict__ Bl,
    float* __restrict__ Cq, bf16* __restrict__ Cv, int K)
{
  __shared__ short sAh[128 * 32], sAl[128 * 32], sBh[128 * 32], sBl[128 * 32];
  const int tid = threadIdx.x, lane = tid & 63, wv = tid >> 6;
  const int rowBase = blockIdx.y * 128, colBase = blockIdx.x * 128;
  const int waveRow = (wv >> 1) * 64, waveCol = (wv & 1) * 64;
  const int stR = tid >> 2, stK = (tid & 3) * 8;

  const bf16* gAh = Ah + (size_t)(rowBase + stR) * K + stK;
  const bf16* gAl = Al + (size_t)(rowBase + stR) * K + stK;
  const bf16* gBh = Bh + (size_t)(colBase + stR) * K + stK;
  const bf16* gBl = Bl + (size_t)(colBase + stR) * K + stK;

  f32x4 acc[4][4];
  #pragma unroll
  for (int r = 0; r < 4; r++)
    #pragma unroll
    for (int c = 0; c < 4; c++) acc[r][c] = (f32x4){0.f, 0.f, 0.f, 0.f};

  const int frow = lane & 15, fk = (lane >> 4) * 8;

  for (int kb = 0; kb < K; kb += 32) {
    __syncthreads();
    #pragma unroll
    for (int j = 0; j < 2; j++) {
      const int lo = j * 2048 + wv * 512;          // LDS elem offset (wave-uniform)
      const size_t go = (size_t)(j * 64) * K + kb; // global elem offset
      gl_lds16(gAh + go, sAh + lo);
      gl_lds16(gAl + go, sAl + lo);
      gl_lds16(gBh + go, sBh + lo);
      gl_lds16(gBl + go, sBl + lo);
    }
    __syncthreads();
    bf16x8 ah[4], al[4], bh[4], bl[4];
    #pragma unroll
    for (int r = 0; r < 4; r++) {
      int ro = (waveRow + r * 16 + frow) * 32 + fk;
      ah[r] = *reinterpret_cast<const bf16x8*>(&sAh[ro]);
      al[r] = *reinterpret_cast<const bf16x8*>(&sAl[ro]);
    }
    #pragma unroll
    for (int c = 0; c < 4; c++) {
      int co = (waveCol + c * 16 + frow) * 32 + fk;
      bh[c] = *reinterpret_cast<const bf16x8*>(&sBh[co]);
      bl[c] = *reinterpret_cast<const bf16x8*>(&sBl[co]);
    }
    #pragma unroll
    for (int r = 0; r < 4; r++)
      #pragma unroll
      for (int c = 0; c < 4; c++) {
        acc[r][c] = __builtin_amdgcn_mfma_f32_16x16x32_bf16(ah[r], bh[c], acc[r][c], 0, 0, 0);
        acc[r][c] = __builtin_amdgcn_mfma_f32_16x16x32_bf16(ah[r], bl[c], acc[r][c], 0, 0, 0);
        acc[r][c] = __builtin_amdgcn_mfma_f32_16x16x32_bf16(al[r], bh[c], acc[r][c], 0, 0, 0);
      }
  }

  const bool isV = (colBase >= 2048);
  #pragma unroll
  for (int r = 0; r < 4; r++)
    #pragma unroll
    for (int c = 0; c < 4; c++) {
      #pragma unroll
      for (int reg = 0; reg < 4; reg++) {
        int row = rowBase + waveRow + r * 16 + (lane >> 4) * 4 + reg;
        int col = colBase + waveCol + c * 16 + (lane & 15);
        float v = acc[r][c][reg];
        if (!isV) Cq[(size_t)row * 2048 + col] = v;
        else      Cv[(size_t)row * 1024 + (col - 2048)] = __float2bfloat16(v);
      }
    }
}

// Plain bf16 NT GEMM + bias, fp32 out. Same structure, single product.
__global__ __launch_bounds__(256) void gemm_bf16_out(
    const bf16* __restrict__ A, const bf16* __restrict__ B,
    const float* __restrict__ bias, float* __restrict__ C, int K, int Mo)
{
  __shared__ short sA[128 * 32], sB[128 * 32];
  const int tid = threadIdx.x, lane = tid & 63, wv = tid >> 6;
  const int rowBase = blockIdx.y * 128, colBase = blockIdx.x * 128;
  const int waveRow = (wv >> 1) * 64, waveCol = (wv & 1) * 64;
  const int stR = tid >> 2, stK = (tid & 3) * 8;
  const bf16* gA = A + (size_t)(rowBase + stR) * K + stK;
  const bf16* gB = B + (size_t)(colBase + stR) * K + stK;

  f32x4 acc[4][4];
  #pragma unroll
  for (int r = 0; r < 4; r++)
    #pragma unroll
    for (int c = 0; c < 4; c++) acc[r][c] = (f32x4){0.f, 0.f, 0.f, 0.f};

  const int frow = lane & 15, fk = (lane >> 4) * 8;

  for (int kb = 0; kb < K; kb += 32) {
    __syncthreads();
    #pragma unroll
    for (int j = 0; j < 2; j++) {
      const int lo = j * 2048 + wv * 512;
      const size_t go = (size_t)(j * 64) * K + kb;
      gl_lds16(gA + go, sA + lo);
      gl_lds16(gB + go, sB + lo);
    }
    __syncthreads();
    bf16x8 a[4], b[4];
    #pragma unroll
    for (int r = 0; r < 4; r++)
      a[r] = *reinterpret_cast<const bf16x8*>(&sA[(waveRow + r * 16 + frow) * 32 + fk]);
    #pragma unroll
    for (int c = 0; c < 4; c++)
      b[c] = *reinterpret_cast<const bf16x8*>(&sB[(waveCol + c * 16 + frow) * 32 + fk]);
    #pragma unroll
    for (int r = 0; r < 4; r++)
      #pragma unroll
      for (int c = 0; c < 4; c++)
        acc[r][c] = __builtin_amdgcn_mfma_f32_16x16x32_bf16(a[r], b[c], acc[r][c], 0, 0, 0);
  }

  #pragma unroll
  for (int r = 0; r < 4; r++)
    #pragma unroll
    for (int c = 0; c < 4; c++)
      #pragma unroll
      for (int reg = 0; reg < 4; reg++) {
        int row = rowBase + waveRow + r * 16 + (lane >> 4) * 4 + reg;
        int col = colBase + waveCol + c * 16 + (lane & 15);
        C[(size_t)row * Mo + col] = acc[r][c][reg] + bias[col];
      }
}

// phi from fused qk buffer (row stride 2048; k at +1024). Writes bf16.
__global__ __launch_bounds__(64) void phi_kernel(
    const float* __restrict__ qk, const float* __restrict__ omega,
    bf16* __restrict__ phiq, bf16* __restrict__ phik)
{
  const int n = blockIdx.x, h = blockIdx.y;
  const int m = threadIdx.x;
  __shared__ float qs[64], ks[64];
  float qv = qk[(size_t)n * 2048 + h * HD + m];
  float kv = qk[(size_t)n * 2048 + 1024 + h * HD + m];
  qs[m] = qv; ks[m] = kv;
  float nq = qv * qv, nk = kv * kv;
  #pragma unroll
  for (int off = 32; off > 0; off >>= 1) {
    nq += __shfl_xor(nq, off);
    nk += __shfl_xor(nk, off);
  }
  __syncthreads();
  float pq = 0.f, pk = 0.f;
  const float4* om = reinterpret_cast<const float4*>(omega + (size_t)m * FM);
  #pragma unroll
  for (int d4 = 0; d4 < 16; d4++) {
    float4 f = om[d4];
    pq += qs[d4 * 4 + 0] * f.x + qs[d4 * 4 + 1] * f.y
        + qs[d4 * 4 + 2] * f.z + qs[d4 * 4 + 3] * f.w;
    pk += ks[d4 * 4 + 0] * f.x + ks[d4 * 4 + 1] * f.y
        + ks[d4 * 4 + 2] * f.z + ks[d4 * 4 + 3] * f.w;
  }
  size_t o = ((size_t)h * N_TOK + n) * FM + m;
  phiq[o] = __float2bfloat16(__expf(fminf(pq - 0.5f * nq, 80.f)) * 0.125f);
  phik[o] = __float2bfloat16(__expf(fminf(pk - 0.5f * nk, 80.f)) * 0.125f);
}

__global__ __launch_bounds__(256) void chunk_sum(
    const bf16* __restrict__ phik, const bf16* __restrict__ vf,
    float* __restrict__ ckv, float* __restrict__ ck)
{
  const int c = blockIdx.x, h = blockIdx.y;
  __shared__ float sPk[64][65];
  __shared__ float sV[64][65];
  const int tid = threadIdx.x;
  for (int t = tid; t < 4096; t += 256) {
    int j = t >> 6, e = t & 63;
    sPk[j][e] = b2f(phik[((size_t)h * N_TOK + c * CS + j) * FM + e]);
    sV[j][e]  = b2f(vf[(size_t)(c * CS + j) * DIMM + h * HD + e]);
  }
  __syncthreads();
  const int tx = tid & 15, ty = tid >> 4;
  const int m0 = ty * 4, d0 = tx * 4;
  float acc[4][4] = {};
  for (int j = 0; j < 64; j++) {
    float p[4], v[4];
    #pragma unroll
    for (int u = 0; u < 4; u++) { p[u] = sPk[j][m0 + u]; v[u] = sV[j][d0 + u]; }
    #pragma unroll
    for (int u = 0; u < 4; u++)
      #pragma unroll
      for (int w = 0; w < 4; w++) acc[u][w] += p[u] * v[w];
  }
  float* dst = ckv + ((size_t)h * NC + c) * FM * HD;
  #pragma unroll
  for (int u = 0; u < 4; u++)
    #pragma unroll
    for (int w = 0; w < 4; w++) dst[(m0 + u) * HD + d0 + w] = acc[u][w];
  if (tid < 64) {
    float s = 0.f;
    for (int j = 0; j < 64; j++) s += sPk[j][tid];
    ck[((size_t)h * NC + c) * FM + tid] = s;
  }
}

__global__ __launch_bounds__(256) void prefix_chunks(
    float* __restrict__ ckv, float* __restrict__ ck)
{
  const int h = blockIdx.x, g = blockIdx.y;
  const int cell = g * 256 + threadIdx.x;
  float run = 0.f;
  for (int c = 0; c < NC; c++) {
    size_t idx = ((size_t)h * NC + c) * 4096 + cell;
    float v = ckv[idx]; ckv[idx] = run; run += v;
  }
  if (g == 0 && threadIdx.x < 64) {
    float r2 = 0.f;
    for (int c = 0; c < NC; c++) {
      size_t idx = ((size_t)h * NC + c) * FM + threadIdx.x;
      float v = ck[idx]; ck[idx] = r2; r2 += v;
    }
  }
}

__global__ __launch_bounds__(256) void attn_chunk(
    const bf16* __restrict__ phiq, const bf16* __restrict__ phik,
    const bf16* __restrict__ vf, const float* __restrict__ ckv,
    const float* __restrict__ ck, bf16* __restrict__ attn_out)
{
  const int c = blockIdx.x, h = blockIdx.y;
  __shared__ float sPq[64][65];
  __shared__ float sPk[64][65];
  __shared__ float sV[64][65];
  __shared__ float sS[64][65];
  __shared__ float sKc[64];
  __shared__ float sDen[64];
  const int tid = threadIdx.x;
  const float* ckv_base = ckv + ((size_t)h * NC + c) * 4096;
  for (int t = tid; t < 4096; t += 256) {
    int i = t >> 6, e = t & 63;
    sPq[i][e] = b2f(phiq[((size_t)h * N_TOK + c * CS + i) * FM + e]);
    sPk[i][e] = b2f(phik[((size_t)h * N_TOK + c * CS + i) * FM + e]);
    sV[i][e]  = b2f(vf[(size_t)(c * CS + i) * DIMM + h * HD + e]);
    sS[i][e]  = ckv_base[t];
  }
  if (tid < 64) sKc[tid] = ck[((size_t)h * NC + c) * FM + tid];
  __syncthreads();

  const int tx = tid & 15, ty = tid >> 4;
  const int i0 = ty * 4, j0 = tx * 4;

  float accA[4][4] = {};
  for (int m = 0; m < 64; m++) {
    float a[4], b[4];
    #pragma unroll
    for (int u = 0; u < 4; u++) { a[u] = sPq[i0 + u][m]; b[u] = sPk[j0 + u][m]; }
    #pragma unroll
    for (int u = 0; u < 4; u++)
      #pragma unroll
      for (int w = 0; w < 4; w++) accA[u][w] += a[u] * b[w];
  }
  __syncthreads();
  #pragma unroll
  for (int u = 0; u < 4; u++)
    #pragma unroll
    for (int w = 0; w < 4; w++)
      sPk[i0 + u][j0 + w] = (j0 + w <= i0 + u) ? accA[u][w] : 0.f;
  __syncthreads();

  if (tid < 64) {
    float den = 0.f;
    for (int m = 0; m < 64; m++) den += sPq[tid][m] * sKc[m];
    for (int j = 0; j < 64; j++) den += sPk[tid][j];
    sDen[tid] = 1.f / (den + 1e-6f);
  }
  __syncthreads();

  float accO[4][4] = {};
  for (int j = 0; j < 64; j++) {
    float a[4], v[4];
    #pragma unroll
    for (int u = 0; u < 4; u++) { a[u] = sPk[i0 + u][j]; v[u] = sV[j][j0 + u]; }
    #pragma unroll
    for (int u = 0; u < 4; u++)
      #pragma unroll
      for (int w = 0; w < 4; w++) accO[u][w] += a[u] * v[w];
  }
  for (int m = 0; m < 64; m++) {
    float a[4], s[4];
    #pragma unroll
    for (int u = 0; u < 4; u++) { a[u] = sPq[i0 + u][m]; s[u] = sS[m][j0 + u]; }
    #pragma unroll
    for (int u = 0; u < 4; u++)
      #pragma unroll
      for (int w = 0; w < 4; w++) accO[u][w] += a[u] * s[w];
  }
  #pragma unroll
  for (int u = 0; u < 4; u++) {
    int n = c * CS + i0 + u;
    float inv = sDen[i0 + u];
    uint2 pk2;
    pk2.x = (unsigned)f2bfu(accO[u][0] * inv) | ((unsigned)f2bfu(accO[u][1] * inv) << 16);
    pk2.y = (unsigned)f2bfu(accO[u][2] * inv) | ((unsigned)f2bfu(accO[u][3] * inv) << 16);
    *reinterpret_cast<uint2*>(attn_out + (size_t)n * DIMM + h * HD + j0) = pk2;
  }
}

extern "C" void kernel_launch(void* const* d_in, const int* in_sizes, int n_in,
                              void* d_out, int out_size, void* d_ws, size_t ws_size,
                              hipStream_t stream) {
  (void)in_sizes; (void)n_in; (void)out_size; (void)ws_size;
  const float* x     = (const float*)d_in[0];
  const float* omega = (const float*)d_in[1];
  const float* wq    = (const float*)d_in[2];
  const float* wk    = (const float*)d_in[3];
  const float* wv    = (const float*)d_in[4];
  const float* wo    = (const float*)d_in[5];
  const float* bo    = (const float*)d_in[6];
  float* out = (float*)d_out;

  // Workspace layout, 48.0 MB total (round-2 used 48.125 MB successfully):
  char* w = (char*)d_ws;
  bf16*  x_hi    = (bf16*)(w);                       // 4 MB   [later: attn bf16]
  bf16*  x_lo    = (bf16*)(w + (4u  << 20));         // 4 MB   [later: wo_bf]
  bf16*  wqkv_hi = (bf16*)(w + (8u  << 20));         // 6 MB
  bf16*  wqkv_lo = (bf16*)(w + (14u << 20));         // 6 MB
  float* qk      = (float*)(w + (20u << 20));        // 16 MB  [later: ckv+ck]
  bf16*  vbf     = (bf16*)(w + (36u << 20));         // 4 MB
  bf16*  phiq    = (bf16*)(w + (40u << 20));         // 4 MB
  bf16*  phik    = (bf16*)(w + (44u << 20));         // 4 MB
  float* ckv     = (float*)(w + (20u << 20));        // alias qk (dead after phi)
  float* ck      = (float*)(w + (28u << 20));
  bf16*  attnb   = x_hi;                             // alias (x dead after QKV GEMM)
  bf16*  wo_bf   = x_lo;                             // alias

  // 1. Split conversions
  cvt_split<<<2048, 256, 0, stream>>>((const float4*)x, x_hi, x_lo, 524288);
  cvt_split<<<1024, 256, 0, stream>>>((const float4*)wq, wqkv_hi,           wqkv_lo,           262144);
  cvt_split<<<1024, 256, 0, stream>>>((const float4*)wk, wqkv_hi + 1048576, wqkv_lo + 1048576, 262144);
  cvt_split<<<1024, 256, 0, stream>>>((const float4*)wv, wqkv_hi + 2097152, wqkv_lo + 2097152, 262144);

  // 2. Fused QKV projection (split-bf16 MFMA), N=3072 cols
  gemm_split_qkv<<<dim3(24, 16), 256, 0, stream>>>(x_hi, x_lo, wqkv_hi, wqkv_lo, qk, vbf, DIMM);

  // 3. wo -> bf16 (after QKV GEMM: aliases x_lo)
  cvt_bf<<<1024, 256, 0, stream>>>((const float4*)wo, wo_bf, 262144);

  // 4. Feature map
  phi_kernel<<<dim3(N_TOK, NH), 64, 0, stream>>>(qk, omega, phiq, phik);

  // 5. Chunked causal linear attention
  chunk_sum<<<dim3(NC, NH), 256, 0, stream>>>(phik, vbf, ckv, ck);
  prefix_chunks<<<dim3(NH, 16), 256, 0, stream>>>(ckv, ck);
  attn_chunk<<<dim3(NC, NH), 256, 0, stream>>>(phiq, phik, vbf, ckv, ck, attnb);

  // 6. Output projection (bf16 MFMA) + bias
  gemm_bf16_out<<<dim3(8, 16), 256, 0, stream>>>(attnb, wo_bf, bo, out, DIMM, DIMM);
}

// Round 4
// 209.757 us; speedup vs baseline: 2.5917x; 1.2533x over previous
//
#include <hip/hip_runtime.h>
#include <hip/hip_bf16.h>

typedef __hip_bfloat16 bf16;
typedef __attribute__((ext_vector_type(8))) short bf16x8;
typedef __attribute__((ext_vector_type(4))) float f32x4;

constexpr int N_TOK = 2048;
constexpr int DIMM  = 1024;
constexpr int NH    = 16;
constexpr int HD    = 64;
constexpr int FM    = 64;
constexpr int NC    = 32;
constexpr int CS    = 64;

__device__ __forceinline__ float b2f(bf16 v) { return __bfloat162float(v); }
__device__ __forceinline__ unsigned short f2bfu(float v) {
  bf16 h = __float2bfloat16(v);
  return *reinterpret_cast<unsigned short*>(&h);
}

// async global->LDS, 16B per lane. LDS dest = wave-uniform base + lane*16B.
__device__ __forceinline__ void gl_lds16(const bf16* g, short* l) {
  __builtin_amdgcn_global_load_lds(
      (const __attribute__((address_space(1))) void*)g,
      (__attribute__((address_space(3))) void*)l, 16, 0, 0);
}

// fp32 -> bf16 hi/lo split (vectorized by 4)
__global__ __launch_bounds__(256) void cvt_split(
    const float4* __restrict__ src, bf16* __restrict__ hi, bf16* __restrict__ lo, int n4)
{
  int i = blockIdx.x * 256 + threadIdx.x;
  if (i >= n4) return;
  float4 v = src[i];
  float f[4] = {v.x, v.y, v.z, v.w};
  unsigned short h[4], l[4];
  #pragma unroll
  for (int j = 0; j < 4; j++) {
    bf16 hb = __float2bfloat16(f[j]);
    h[j] = *reinterpret_cast<unsigned short*>(&hb);
    l[j] = f2bfu(f[j] - b2f(hb));
  }
  uint2 ph, pl;
  ph.x = (unsigned)h[0] | ((unsigned)h[1] << 16);
  ph.y = (unsigned)h[2] | ((unsigned)h[3] << 16);
  pl.x = (unsigned)l[0] | ((unsigned)l[1] << 16);
  pl.y = (unsigned)l[2] | ((unsigned)l[3] << 16);
  reinterpret_cast<uint2*>(hi)[i] = ph;
  reinterpret_cast<uint2*>(lo)[i] = pl;
}

__global__ __launch_bounds__(256) void cvt_bf(
    const float4* __restrict__ src, bf16* __restrict__ dst, int n4)
{
  int i = blockIdx.x * 256 + threadIdx.x;
  if (i >= n4) return;
  float4 v = src[i];
  uint2 p;
  p.x = (unsigned)f2bfu(v.x) | ((unsigned)f2bfu(v.y) << 16);
  p.y = (unsigned)f2bfu(v.z) | ((unsigned)f2bfu(v.w) << 16);
  reinterpret_cast<uint2*>(dst)[i] = p;
}

// Split-bf16 NT GEMM: C[n][m] = sum_k (Ah+Al)[n][k]*(Bh+Bl)[m][k] (minus lo*lo).
__global__ __launch_bounds__(256) void gemm_split_qkv(
    const bf16* __restrict__ Ah, const bf16* __restrict__ Al,
    const bf16* __restrict__ Bh, const bf16* __restrict__ Bl,
    float* __restrict__ Cq, bf16* __restrict__ Cv, int K)
{
  __shared__ short sAh[128 * 32], sAl[128 * 32], sBh[128 * 32], sBl[128 * 32];
  const int tid = threadIdx.x, lane = tid & 63, wv = tid >> 6;
  const int rowBase = blockIdx.y * 128, colBase = blockIdx.x * 128;
  const int waveRow = (wv >> 1) * 64, waveCol = (wv & 1) * 64;
  const int stR = tid >> 2, stK = (tid & 3) * 8;

  const bf16* gAh = Ah + (size_t)(rowBase + stR) * K + stK;
  const bf16* gAl = Al + (size_t)(rowBase + stR) * K + stK;
  const bf16* gBh = Bh + (size_t)(colBase + stR) * K + stK;
  const bf16* gBl = Bl + (size_t)(colBase + stR) * K + stK;

  f32x4 acc[4][4];
  #pragma unroll
  for (int r = 0; r < 4; r++)
    #pragma unroll
    for (int c = 0; c < 4; c++) acc[r][c] = (f32x4){0.f, 0.f, 0.f, 0.f};

  const int frow = lane & 15, fk = (lane >> 4) * 8;

  for (int kb = 0; kb < K; kb += 32) {
    __syncthreads();
    #pragma unroll
    for (int j = 0; j < 2; j++) {
      const int lo = j * 2048 + wv * 512;
      const size_t go = (size_t)(j * 64) * K + kb;
      gl_lds16(gAh + go, sAh + lo);
      gl_lds16(gAl + go, sAl + lo);
      gl_lds16(gBh + go, sBh + lo);
      gl_lds16(gBl + go, sBl + lo);
    }
    __syncthreads();
    bf16x8 ah[4], al[4], bh[4], bl[4];
    #pragma unroll
    for (int r = 0; r < 4; r++) {
      int ro = (waveRow + r * 16 + frow) * 32 + fk;
      ah[r] = *reinterpret_cast<const bf16x8*>(&sAh[ro]);
      al[r] = *reinterpret_cast<const bf16x8*>(&sAl[ro]);
    }
    #pragma unroll
    for (int c = 0; c < 4; c++) {
      int co = (waveCol + c * 16 + frow) * 32 + fk;
      bh[c] = *reinterpret_cast<const bf16x8*>(&sBh[co]);
      bl[c] = *reinterpret_cast<const bf16x8*>(&sBl[co]);
    }
    #pragma unroll
    for (int r = 0; r < 4; r++)
      #pragma unroll
      for (int c = 0; c < 4; c++) {
        acc[r][c] = __builtin_amdgcn_mfma_f32_16x16x32_bf16(ah[r], bh[c], acc[r][c], 0, 0, 0);
        acc[r][c] = __builtin_amdgcn_mfma_f32_16x16x32_bf16(ah[r], bl[c], acc[r][c], 0, 0, 0);
        acc[r][c] = __builtin_amdgcn_mfma_f32_16x16x32_bf16(al[r], bh[c], acc[r][c], 0, 0, 0);
      }
  }

  const bool isV = (colBase >= 2048);
  #pragma unroll
  for (int r = 0; r < 4; r++)
    #pragma unroll
    for (int c = 0; c < 4; c++) {
      #pragma unroll
      for (int reg = 0; reg < 4; reg++) {
        int row = rowBase + waveRow + r * 16 + (lane >> 4) * 4 + reg;
        int col = colBase + waveCol + c * 16 + (lane & 15);
        float v = acc[r][c][reg];
        if (!isV) Cq[(size_t)row * 2048 + col] = v;
        else      Cv[(size_t)row * 1024 + (col - 2048)] = __float2bfloat16(v);
      }
    }
}

// Plain bf16 NT GEMM + bias, fp32 out.
__global__ __launch_bounds__(256) void gemm_bf16_out(
    const bf16* __restrict__ A, const bf16* __restrict__ B,
    const float* __restrict__ bias, float* __restrict__ C, int K, int Mo)
{
  __shared__ short sA[128 * 32], sB[128 * 32];
  const int tid = threadIdx.x, lane = tid & 63, wv = tid >> 6;
  const int rowBase = blockIdx.y * 128, colBase = blockIdx.x * 128;
  const int waveRow = (wv >> 1) * 64, waveCol = (wv & 1) * 64;
  const int stR = tid >> 2, stK = (tid & 3) * 8;
  const bf16* gA = A + (size_t)(rowBase + stR) * K + stK;
  const bf16* gB = B + (size_t)(colBase + stR) * K + stK;

  f32x4 acc[4][4];
  #pragma unroll
  for (int r = 0; r < 4; r++)
    #pragma unroll
    for (int c = 0; c < 4; c++) acc[r][c] = (f32x4){0.f, 0.f, 0.f, 0.f};

  const int frow = lane & 15, fk = (lane >> 4) * 8;

  for (int kb = 0; kb < K; kb += 32) {
    __syncthreads();
    #pragma unroll
    for (int j = 0; j < 2; j++) {
      const int lo = j * 2048 + wv * 512;
      const size_t go = (size_t)(j * 64) * K + kb;
      gl_lds16(gA + go, sA + lo);
      gl_lds16(gB + go, sB + lo);
    }
    __syncthreads();
    bf16x8 a[4], b[4];
    #pragma unroll
    for (int r = 0; r < 4; r++)
      a[r] = *reinterpret_cast<const bf16x8*>(&sA[(waveRow + r * 16 + frow) * 32 + fk]);
    #pragma unroll
    for (int c = 0; c < 4; c++)
      b[c] = *reinterpret_cast<const bf16x8*>(&sB[(waveCol + c * 16 + frow) * 32 + fk]);
    #pragma unroll
    for (int r = 0; r < 4; r++)
      #pragma unroll
      for (int c = 0; c < 4; c++)
        acc[r][c] = __builtin_amdgcn_mfma_f32_16x16x32_bf16(a[r], b[c], acc[r][c], 0, 0, 0);
  }

  #pragma unroll
  for (int r = 0; r < 4; r++)
    #pragma unroll
    for (int c = 0; c < 4; c++)
      #pragma unroll
      for (int reg = 0; reg < 4; reg++) {
        int row = rowBase + waveRow + r * 16 + (lane >> 4) * 4 + reg;
        int col = colBase + waveCol + c * 16 + (lane & 15);
        C[(size_t)row * Mo + col] = acc[r][c][reg] + bias[col];
      }
}

// MFMA phi: proj = Q_h [128x64] x omega [64x64] (NT), split-bf16, then
// phi = exp(proj - 0.5*||q||^2) / 8, stored bf16 [h][n][m].
// grid (N_TOK/128, NH, 2): z=0 -> q -> phiq, z=1 -> k -> phik.
// LDS rows padded to 72 elems (144 B, 16B-aligned) to break bank aliasing.
__global__ __launch_bounds__(256) void phi_mfma(
    const float* __restrict__ qk, const float* __restrict__ omega,
    bf16* __restrict__ phiq, bf16* __restrict__ phik)
{
  constexpr int LD = 72;
  __shared__ short sAh[128 * LD], sAl[128 * LD];
  __shared__ short sBh[64 * LD],  sBl[64 * LD];
  __shared__ float sPart[128][2];

  const int tid = threadIdx.x, lane = tid & 63, wv = tid >> 6;
  const int n0 = blockIdx.x * 128, h = blockIdx.y, z = blockIdx.z;
  const int colOff = z * 1024 + h * HD;

  // Stage A (q or k rows): 2 threads per row, 32 floats each; fp32 norm partial.
  {
    const int r = tid >> 1, half = tid & 1;
    const float* src = qk + (size_t)(n0 + r) * 2048 + colOff + half * 32;
    float ssq = 0.f;
    #pragma unroll
    for (int j4 = 0; j4 < 8; j4++) {
      float4 v = reinterpret_cast<const float4*>(src)[j4];
      float f[4] = {v.x, v.y, v.z, v.w};
      unsigned short hh[4], ll[4];
      #pragma unroll
      for (int j = 0; j < 4; j++) {
        ssq += f[j] * f[j];
        bf16 hb = __float2bfloat16(f[j]);
        hh[j] = *reinterpret_cast<unsigned short*>(&hb);
        ll[j] = f2bfu(f[j] - b2f(hb));
      }
      int o = r * LD + half * 32 + j4 * 4;
      uint2 ph = { (unsigned)hh[0] | ((unsigned)hh[1] << 16),
                   (unsigned)hh[2] | ((unsigned)hh[3] << 16) };
      uint2 pl = { (unsigned)ll[0] | ((unsigned)ll[1] << 16),
                   (unsigned)ll[2] | ((unsigned)ll[3] << 16) };
      *reinterpret_cast<uint2*>(&sAh[o]) = ph;
      *reinterpret_cast<uint2*>(&sAl[o]) = pl;
    }
    sPart[r][half] = ssq;
  }
  // Stage B (omega): 4 threads per row, 16 floats each.
  {
    const int r = tid >> 2, q4 = tid & 3;
    const float* src = omega + (size_t)r * FM + q4 * 16;
    #pragma unroll
    for (int j4 = 0; j4 < 4; j4++) {
      float4 v = reinterpret_cast<const float4*>(src)[j4];
      float f[4] = {v.x, v.y, v.z, v.w};
      unsigned short hh[4], ll[4];
      #pragma unroll
      for (int j = 0; j < 4; j++) {
        bf16 hb = __float2bfloat16(f[j]);
        hh[j] = *reinterpret_cast<unsigned short*>(&hb);
        ll[j] = f2bfu(f[j] - b2f(hb));
      }
      int o = r * LD + q4 * 16 + j4 * 4;
      uint2 ph = { (unsigned)hh[0] | ((unsigned)hh[1] << 16),
                   (unsigned)hh[2] | ((unsigned)hh[3] << 16) };
      uint2 pl = { (unsigned)ll[0] | ((unsigned)ll[1] << 16),
                   (unsigned)ll[2] | ((unsigned)ll[3] << 16) };
      *reinterpret_cast<uint2*>(&sBh[o]) = ph;
      *reinterpret_cast<uint2*>(&sBl[o]) = pl;
    }
  }
  __syncthreads();

  // 4 waves: 2x2 -> waveRow in {0,64}, waveCol in {0,32}.
  const int waveRow = (wv >> 1) * 64, waveCol = (wv & 1) * 32;
  const int frow = lane & 15, fk = (lane >> 4) * 8;

  f32x4 acc[4][2];
  #pragma unroll
  for (int r = 0; r < 4; r++)
    #pragma unroll
    for (int c = 0; c < 2; c++) acc[r][c] = (f32x4){0.f, 0.f, 0.f, 0.f};

  #pragma unroll
  for (int ks = 0; ks < 64; ks += 32) {
    bf16x8 ah[4], al[4], bh[2], bl[2];
    #pragma unroll
    for (int r = 0; r < 4; r++) {
      int o = (waveRow + r * 16 + frow) * LD + ks + fk;
      ah[r] = *reinterpret_cast<const bf16x8*>(&sAh[o]);
      al[r] = *reinterpret_cast<const bf16x8*>(&sAl[o]);
    }
    #pragma unroll
    for (int c = 0; c < 2; c++) {
      int o = (waveCol + c * 16 + frow) * LD + ks + fk;
      bh[c] = *reinterpret_cast<const bf16x8*>(&sBh[o]);
      bl[c] = *reinterpret_cast<const bf16x8*>(&sBl[o]);
    }
    #pragma unroll
    for (int r = 0; r < 4; r++)
      #pragma unroll
      for (int c = 0; c < 2; c++) {
        acc[r][c] = __builtin_amdgcn_mfma_f32_16x16x32_bf16(ah[r], bh[c], acc[r][c], 0, 0, 0);
        acc[r][c] = __builtin_amdgcn_mfma_f32_16x16x32_bf16(ah[r], bl[c], acc[r][c], 0, 0, 0);
        acc[r][c] = __builtin_amdgcn_mfma_f32_16x16x32_bf16(al[r], bh[c], acc[r][c], 0, 0, 0);
      }
  }

  bf16* dst = z ? phik : phiq;
  #pragma unroll
  for (int r = 0; r < 4; r++)
    #pragma unroll
    for (int c = 0; c < 2; c++)
      #pragma unroll
      for (int reg = 0; reg < 4; reg++) {
        int row = waveRow + r * 16 + (lane >> 4) * 4 + reg;
        int col = waveCol + c * 16 + (lane & 15);
        float norm = 0.5f * (sPart[row][0] + sPart[row][1]);
        float v = __expf(fminf(acc[r][c][reg] - norm, 80.f)) * 0.125f;
        dst[((size_t)h * N_TOK + n0 + row) * FM + col] = __float2bfloat16(v);
      }
}

__global__ __launch_bounds__(256) void chunk_sum(
    const bf16* __restrict__ phik, const bf16* __restrict__ vf,
    float* __restrict__ ckv, float* __restrict__ ck)
{
  const int c = blockIdx.x, h = blockIdx.y;
  __shared__ float sPk[64][65];
  __shared__ float sV[64][65];
  const int tid = threadIdx.x;
  for (int t = tid; t < 4096; t += 256) {
    int j = t >> 6, e = t & 63;
    sPk[j][e] = b2f(phik[((size_t)h * N_TOK + c * CS + j) * FM + e]);
    sV[j][e]  = b2f(vf[(size_t)(c * CS + j) * DIMM + h * HD + e]);
  }
  __syncthreads();
  const int tx = tid & 15, ty = tid >> 4;
  const int m0 = ty * 4, d0 = tx * 4;
  float acc[4][4] = {};
  for (int j = 0; j < 64; j++) {
    float p[4], v[4];
    #pragma unroll
    for (int u = 0; u < 4; u++) { p[u] = sPk[j][m0 + u]; v[u] = sV[j][d0 + u]; }
    #pragma unroll
    for (int u = 0; u < 4; u++)
      #pragma unroll
      for (int w = 0; w < 4; w++) acc[u][w] += p[u] * v[w];
  }
  float* dst = ckv + ((size_t)h * NC + c) * FM * HD;
  #pragma unroll
  for (int u = 0; u < 4; u++)
    #pragma unroll
    for (int w = 0; w < 4; w++) dst[(m0 + u) * HD + d0 + w] = acc[u][w];
  if (tid < 64) {
    float s = 0.f;
    for (int j = 0; j < 64; j++) s += sPk[j][tid];
    ck[((size_t)h * NC + c) * FM + tid] = s;
  }
}

__global__ __launch_bounds__(256) void prefix_chunks(
    float* __restrict__ ckv, float* __restrict__ ck)
{
  const int h = blockIdx.x, g = blockIdx.y;
  const int cell = g * 256 + threadIdx.x;
  float run = 0.f;
  for (int c = 0; c < NC; c++) {
    size_t idx = ((size_t)h * NC + c) * 4096 + cell;
    float v = ckv[idx]; ckv[idx] = run; run += v;
  }
  if (g == 0 && threadIdx.x < 64) {
    float r2 = 0.f;
    for (int c = 0; c < NC; c++) {
      size_t idx = ((size_t)h * NC + c) * FM + threadIdx.x;
      float v = ck[idx]; ck[idx] = r2; r2 += v;
    }
  }
}

__global__ __launch_bounds__(256) void attn_chunk(
    const bf16* __restrict__ phiq, const bf16* __restrict__ phik,
    const bf16* __restrict__ vf, const float* __restrict__ ckv,
    const float* __restrict__ ck, bf16* __restrict__ attn_out)
{
  const int c = blockIdx.x, h = blockIdx.y;
  __shared__ float sPq[64][65];
  __shared__ float sPk[64][65];
  __shared__ float sV[64][65];
  __shared__ float sS[64][65];
  __shared__ float sKc[64];
  __shared__ float sDen[64];
  const int tid = threadIdx.x;
  const float* ckv_base = ckv + ((size_t)h * NC + c) * 4096;
  for (int t = tid; t < 4096; t += 256) {
    int i = t >> 6, e = t & 63;
    sPq[i][e] = b2f(phiq[((size_t)h * N_TOK + c * CS + i) * FM + e]);
    sPk[i][e] = b2f(phik[((size_t)h * N_TOK + c * CS + i) * FM + e]);
    sV[i][e]  = b2f(vf[(size_t)(c * CS + i) * DIMM + h * HD + e]);
    sS[i][e]  = ckv_base[t];
  }
  if (tid < 64) sKc[tid] = ck[((size_t)h * NC + c) * FM + tid];
  __syncthreads();

  const int tx = tid & 15, ty = tid >> 4;
  const int i0 = ty * 4, j0 = tx * 4;

  float accA[4][4] = {};
  for (int m = 0; m < 64; m++) {
    float a[4], b[4];
    #pragma unroll
    for (int u = 0; u < 4; u++) { a[u] = sPq[i0 + u][m]; b[u] = sPk[j0 + u][m]; }
    #pragma unroll
    for (int u = 0; u < 4; u++)
      #pragma unroll
      for (int w = 0; w < 4; w++) accA[u][w] += a[u] * b[w];
  }
  __syncthreads();
  #pragma unroll
  for (int u = 0; u < 4; u++)
    #pragma unroll
    for (int w = 0; w < 4; w++)
      sPk[i0 + u][j0 + w] = (j0 + w <= i0 + u) ? accA[u][w] : 0.f;
  __syncthreads();

  if (tid < 64) {
    float den = 0.f;
    for (int m = 0; m < 64; m++) den += sPq[tid][m] * sKc[m];
    for (int j = 0; j < 64; j++) den += sPk[tid][j];
    sDen[tid] = 1.f / (den + 1e-6f);
  }
  __syncthreads();

  float accO[4][4] = {};
  for (int j = 0; j < 64; j++) {
    float a[4], v[4];
    #pragma unroll
    for (int u = 0; u < 4; u++) { a[u] = sPk[i0 + u][j]; v[u] = sV[j][j0 + u]; }
    #pragma unroll
    for (int u = 0; u < 4; u++)
      #pragma unroll
      for (int w = 0; w < 4; w++) accO[u][w] += a[u] * v[w];
  }
  for (int m = 0; m < 64; m++) {
    float a[4], s[4];
    #pragma unroll
    for (int u = 0; u < 4; u++) { a[u] = sPq[i0 + u][m]; s[u] = sS[m][j0 + u]; }
    #pragma unroll
    for (int u = 0; u < 4; u++)
      #pragma unroll
      for (int w = 0; w < 4; w++) accO[u][w] += a[u] * s[w];
  }
  #pragma unroll
  for (int u = 0; u < 4; u++) {
    int n = c * CS + i0 + u;
    float inv = sDen[i0 + u];
    uint2 pk2;
    pk2.x = (unsigned)f2bfu(accO[u][0] * inv) | ((unsigned)f2bfu(accO[u][1] * inv) << 16);
    pk2.y = (unsigned)f2bfu(accO[u][2] * inv) | ((unsigned)f2bfu(accO[u][3] * inv) << 16);
    *reinterpret_cast<uint2*>(attn_out + (size_t)n * DIMM + h * HD + j0) = pk2;
  }
}

extern "C" void kernel_launch(void* const* d_in, const int* in_sizes, int n_in,
                              void* d_out, int out_size, void* d_ws, size_t ws_size,
                              hipStream_t stream) {
  (void)in_sizes; (void)n_in; (void)out_size; (void)ws_size;
  const float* x     = (const float*)d_in[0];
  const float* omega = (const float*)d_in[1];
  const float* wq    = (const float*)d_in[2];
  const float* wk    = (const float*)d_in[3];
  const float* wv    = (const float*)d_in[4];
  const float* wo    = (const float*)d_in[5];
  const float* bo    = (const float*)d_in[6];
  float* out = (float*)d_out;

  char* w = (char*)d_ws;
  bf16*  x_hi    = (bf16*)(w);                       // 4 MB   [later: attn bf16]
  bf16*  x_lo    = (bf16*)(w + (4u  << 20));         // 4 MB   [later: wo_bf]
  bf16*  wqkv_hi = (bf16*)(w + (8u  << 20));         // 6 MB
  bf16*  wqkv_lo = (bf16*)(w + (14u << 20));         // 6 MB
  float* qk      = (float*)(w + (20u << 20));        // 16 MB  [later: ckv+ck]
  bf16*  vbf     = (bf16*)(w + (36u << 20));         // 4 MB
  bf16*  phiq    = (bf16*)(w + (40u << 20));         // 4 MB
  bf16*  phik    = (bf16*)(w + (44u << 20));         // 4 MB
  float* ckv     = (float*)(w + (20u << 20));        // alias qk (dead after phi)
  float* ck      = (float*)(w + (28u << 20));
  bf16*  attnb   = x_hi;                             // alias (x dead after QKV GEMM)
  bf16*  wo_bf   = x_lo;                             // alias

  cvt_split<<<2048, 256, 0, stream>>>((const float4*)x, x_hi, x_lo, 524288);
  cvt_split<<<1024, 256, 0, stream>>>((const float4*)wq, wqkv_hi,           wqkv_lo,           262144);
  cvt_split<<<1024, 256, 0, stream>>>((const float4*)wk, wqkv_hi + 1048576, wqkv_lo + 1048576, 262144);
  cvt_split<<<1024, 256, 0, stream>>>((const float4*)wv, wqkv_hi + 2097152, wqkv_lo + 2097152, 262144);

  gemm_split_qkv<<<dim3(24, 16), 256, 0, stream>>>(x_hi, x_lo, wqkv_hi, wqkv_lo, qk, vbf, DIMM);

  cvt_bf<<<1024, 256, 0, stream>>>((const float4*)wo, wo_bf, 262144);

  phi_mfma<<<dim3(N_TOK / 128, NH, 2), 256, 0, stream>>>(qk, omega, phiq, phik);

  chunk_sum<<<dim3(NC, NH), 256, 0, stream>>>(phik, vbf, ckv, ck);
  prefix_chunks<<<dim3(NH, 16), 256, 0, stream>>>(ckv, ck);
  attn_chunk<<<dim3(NC, NH), 256, 0, stream>>>(phiq, phik, vbf, ckv, ck, attnb);

  gemm_bf16_out<<<dim3(8, 16), 256, 0, stream>>>(attnb, wo_bf, bo, out, DIMM, DIMM);
}

// Round 5
// 205.746 us; speedup vs baseline: 2.6422x; 1.0195x over previous
//
#include <hip/hip_runtime.h>
#include <hip/hip_bf16.h>

typedef __hip_bfloat16 bf16;
typedef __attribute__((ext_vector_type(8))) short bf16x8;
typedef __attribute__((ext_vector_type(4))) float f32x4;

constexpr int N_TOK = 2048;
constexpr int DIMM  = 1024;
constexpr int NH    = 16;
constexpr int HD    = 64;
constexpr int FM    = 64;
constexpr int NC    = 32;
constexpr int CS    = 64;

__device__ __forceinline__ float b2f(bf16 v) { return __bfloat162float(v); }
__device__ __forceinline__ unsigned short f2bfu(float v) {
  bf16 h = __float2bfloat16(v);
  return *reinterpret_cast<unsigned short*>(&h);
}

// async global->LDS, 16B per lane. LDS dest = wave-uniform base + lane*16B.
__device__ __forceinline__ void gl_lds16(const bf16* g, short* l) {
  __builtin_amdgcn_global_load_lds(
      (const __attribute__((address_space(1))) void*)g,
      (__attribute__((address_space(3))) void*)l, 16, 0, 0);
}

__device__ __forceinline__ void split_pack(const float4 v, uint2& ph, uint2& pl) {
  float f[4] = {v.x, v.y, v.z, v.w};
  unsigned short h[4], l[4];
  #pragma unroll
  for (int j = 0; j < 4; j++) {
    bf16 hb = __float2bfloat16(f[j]);
    h[j] = *reinterpret_cast<unsigned short*>(&hb);
    l[j] = f2bfu(f[j] - b2f(hb));
  }
  ph.x = (unsigned)h[0] | ((unsigned)h[1] << 16);
  ph.y = (unsigned)h[2] | ((unsigned)h[3] << 16);
  pl.x = (unsigned)l[0] | ((unsigned)l[1] << 16);
  pl.y = (unsigned)l[2] | ((unsigned)l[3] << 16);
}

// One fused conversion pass: x, wq, wk, wv -> hi/lo splits. Quad-indexed.
__global__ __launch_bounds__(256) void cvt_all(
    const float4* __restrict__ x, const float4* __restrict__ wq,
    const float4* __restrict__ wk, const float4* __restrict__ wv,
    bf16* __restrict__ x_hi, bf16* __restrict__ x_lo,
    bf16* __restrict__ w_hi, bf16* __restrict__ w_lo)
{
  int i = blockIdx.x * 256 + threadIdx.x;   // < 1310720
  const float4* src; bf16* hi; bf16* lo; int j;
  if (i < 524288)       { src = x;  j = i;           hi = x_hi;           lo = x_lo; }
  else if (i < 786432)  { src = wq; j = i - 524288;  hi = w_hi;           lo = w_lo; }
  else if (i < 1048576) { src = wk; j = i - 786432;  hi = w_hi + 1048576; lo = w_lo + 1048576; }
  else                  { src = wv; j = i - 1048576; hi = w_hi + 2097152; lo = w_lo + 2097152; }
  uint2 ph, pl;
  split_pack(src[j], ph, pl);
  reinterpret_cast<uint2*>(hi)[j] = ph;
  reinterpret_cast<uint2*>(lo)[j] = pl;
}

__global__ __launch_bounds__(256) void cvt_bf(
    const float4* __restrict__ src, bf16* __restrict__ dst, int n4)
{
  int i = blockIdx.x * 256 + threadIdx.x;
  if (i >= n4) return;
  float4 v = src[i];
  uint2 p;
  p.x = (unsigned)f2bfu(v.x) | ((unsigned)f2bfu(v.y) << 16);
  p.y = (unsigned)f2bfu(v.z) | ((unsigned)f2bfu(v.w) << 16);
  reinterpret_cast<uint2*>(dst)[i] = p;
}

// Split-bf16 NT GEMM, double-buffered LDS.
// C = (Ah+Al)*(Bh+Bl)^T (minus lo*lo). 128x128 tile, BK=32, 4 waves.
__global__ __launch_bounds__(256) void gemm_split_qkv(
    const bf16* __restrict__ Ah, const bf16* __restrict__ Al,
    const bf16* __restrict__ Bh, const bf16* __restrict__ Bl,
    float* __restrict__ Cq, bf16* __restrict__ Cv, int K)
{
  __shared__ short sAh[2][4096], sAl[2][4096], sBh[2][4096], sBl[2][4096];
  const int tid = threadIdx.x, lane = tid & 63, wv = tid >> 6;
  const int rowBase = blockIdx.y * 128, colBase = blockIdx.x * 128;
  const int waveRow = (wv >> 1) * 64, waveCol = (wv & 1) * 64;
  const int stR = tid >> 2, stK = (tid & 3) * 8;

  const bf16* gAh = Ah + (size_t)(rowBase + stR) * K + stK;
  const bf16* gAl = Al + (size_t)(rowBase + stR) * K + stK;
  const bf16* gBh = Bh + (size_t)(colBase + stR) * K + stK;
  const bf16* gBl = Bl + (size_t)(colBase + stR) * K + stK;
  const int ldsOff0 = wv * 512, ldsOff1 = 2048 + wv * 512;

  f32x4 acc[4][4];
  #pragma unroll
  for (int r = 0; r < 4; r++)
    #pragma unroll
    for (int c = 0; c < 4; c++) acc[r][c] = (f32x4){0.f, 0.f, 0.f, 0.f};

  const int frow = lane & 15, fk = (lane >> 4) * 8;
  const int nIter = K / 32;

  // prologue: stage iter 0 into buffer 0
  {
    gl_lds16(gAh, &sAh[0][ldsOff0]); gl_lds16(gAh + (size_t)64 * K, &sAh[0][ldsOff1]);
    gl_lds16(gAl, &sAl[0][ldsOff0]); gl_lds16(gAl + (size_t)64 * K, &sAl[0][ldsOff1]);
    gl_lds16(gBh, &sBh[0][ldsOff0]); gl_lds16(gBh + (size_t)64 * K, &sBh[0][ldsOff1]);
    gl_lds16(gBl, &sBl[0][ldsOff0]); gl_lds16(gBl + (size_t)64 * K, &sBl[0][ldsOff1]);
  }

  int buf = 0;
  for (int it = 0; it < nIter; it++) {
    __syncthreads();   // drains stage(buf); protects buf^1 from overwrite
    if (it + 1 < nIter) {
      const size_t kb = (size_t)(it + 1) * 32;
      const int nb = buf ^ 1;
      gl_lds16(gAh + kb, &sAh[nb][ldsOff0]); gl_lds16(gAh + (size_t)64 * K + kb, &sAh[nb][ldsOff1]);
      gl_lds16(gAl + kb, &sAl[nb][ldsOff0]); gl_lds16(gAl + (size_t)64 * K + kb, &sAl[nb][ldsOff1]);
      gl_lds16(gBh + kb, &sBh[nb][ldsOff0]); gl_lds16(gBh + (size_t)64 * K + kb, &sBh[nb][ldsOff1]);
      gl_lds16(gBl + kb, &sBl[nb][ldsOff0]); gl_lds16(gBl + (size_t)64 * K + kb, &sBl[nb][ldsOff1]);
    }
    bf16x8 ah[4], al[4], bh[4], bl[4];
    #pragma unroll
    for (int r = 0; r < 4; r++) {
      int ro = (waveRow + r * 16 + frow) * 32 + fk;
      ah[r] = *reinterpret_cast<const bf16x8*>(&sAh[buf][ro]);
      al[r] = *reinterpret_cast<const bf16x8*>(&sAl[buf][ro]);
    }
    #pragma unroll
    for (int c = 0; c < 4; c++) {
      int co = (waveCol + c * 16 + frow) * 32 + fk;
      bh[c] = *reinterpret_cast<const bf16x8*>(&sBh[buf][co]);
      bl[c] = *reinterpret_cast<const bf16x8*>(&sBl[buf][co]);
    }
    #pragma unroll
    for (int r = 0; r < 4; r++)
      #pragma unroll
      for (int c = 0; c < 4; c++) {
        acc[r][c] = __builtin_amdgcn_mfma_f32_16x16x32_bf16(ah[r], bh[c], acc[r][c], 0, 0, 0);
        acc[r][c] = __builtin_amdgcn_mfma_f32_16x16x32_bf16(ah[r], bl[c], acc[r][c], 0, 0, 0);
        acc[r][c] = __builtin_amdgcn_mfma_f32_16x16x32_bf16(al[r], bh[c], acc[r][c], 0, 0, 0);
      }
    buf ^= 1;
  }

  const bool isV = (colBase >= 2048);
  #pragma unroll
  for (int r = 0; r < 4; r++)
    #pragma unroll
    for (int c = 0; c < 4; c++) {
      #pragma unroll
      for (int reg = 0; reg < 4; reg++) {
        int row = rowBase + waveRow + r * 16 + (lane >> 4) * 4 + reg;
        int col = colBase + waveCol + c * 16 + (lane & 15);
        float v = acc[r][c][reg];
        if (!isV) Cq[(size_t)row * 2048 + col] = v;
        else      Cv[(size_t)row * 1024 + (col - 2048)] = __float2bfloat16(v);
      }
    }
}

// Plain bf16 NT GEMM + bias, fp32 out, double-buffered LDS.
__global__ __launch_bounds__(256) void gemm_bf16_out(
    const bf16* __restrict__ A, const bf16* __restrict__ B,
    const float* __restrict__ bias, float* __restrict__ C, int K, int Mo)
{
  __shared__ short sA[2][4096], sB[2][4096];
  const int tid = threadIdx.x, lane = tid & 63, wv = tid >> 6;
  const int rowBase = blockIdx.y * 128, colBase = blockIdx.x * 128;
  const int waveRow = (wv >> 1) * 64, waveCol = (wv & 1) * 64;
  const int stR = tid >> 2, stK = (tid & 3) * 8;
  const bf16* gA = A + (size_t)(rowBase + stR) * K + stK;
  const bf16* gB = B + (size_t)(colBase + stR) * K + stK;
  const int ldsOff0 = wv * 512, ldsOff1 = 2048 + wv * 512;

  f32x4 acc[4][4];
  #pragma unroll
  for (int r = 0; r < 4; r++)
    #pragma unroll
    for (int c = 0; c < 4; c++) acc[r][c] = (f32x4){0.f, 0.f, 0.f, 0.f};

  const int frow = lane & 15, fk = (lane >> 4) * 8;
  const int nIter = K / 32;

  gl_lds16(gA, &sA[0][ldsOff0]); gl_lds16(gA + (size_t)64 * K, &sA[0][ldsOff1]);
  gl_lds16(gB, &sB[0][ldsOff0]); gl_lds16(gB + (size_t)64 * K, &sB[0][ldsOff1]);

  int buf = 0;
  for (int it = 0; it < nIter; it++) {
    __syncthreads();
    if (it + 1 < nIter) {
      const size_t kb = (size_t)(it + 1) * 32;
      const int nb = buf ^ 1;
      gl_lds16(gA + kb, &sA[nb][ldsOff0]); gl_lds16(gA + (size_t)64 * K + kb, &sA[nb][ldsOff1]);
      gl_lds16(gB + kb, &sB[nb][ldsOff0]); gl_lds16(gB + (size_t)64 * K + kb, &sB[nb][ldsOff1]);
    }
    bf16x8 a[4], b[4];
    #pragma unroll
    for (int r = 0; r < 4; r++)
      a[r] = *reinterpret_cast<const bf16x8*>(&sA[buf][(waveRow + r * 16 + frow) * 32 + fk]);
    #pragma unroll
    for (int c = 0; c < 4; c++)
      b[c] = *reinterpret_cast<const bf16x8*>(&sB[buf][(waveCol + c * 16 + frow) * 32 + fk]);
    #pragma unroll
    for (int r = 0; r < 4; r++)
      #pragma unroll
      for (int c = 0; c < 4; c++)
        acc[r][c] = __builtin_amdgcn_mfma_f32_16x16x32_bf16(a[r], b[c], acc[r][c], 0, 0, 0);
    buf ^= 1;
  }

  #pragma unroll
  for (int r = 0; r < 4; r++)
    #pragma unroll
    for (int c = 0; c < 4; c++)
      #pragma unroll
      for (int reg = 0; reg < 4; reg++) {
        int row = rowBase + waveRow + r * 16 + (lane >> 4) * 4 + reg;
        int col = colBase + waveCol + c * 16 + (lane & 15);
        C[(size_t)row * Mo + col] = acc[r][c][reg] + bias[col];
      }
}

// MFMA phi: proj = Q_h [128x64] x omega [64x64] (NT), split-bf16, then
// phi = exp(proj - 0.5*||q||^2) / 8, stored bf16 [h][n][m].
__global__ __launch_bounds__(256) void phi_mfma(
    const float* __restrict__ qk, const float* __restrict__ omega,
    bf16* __restrict__ phiq, bf16* __restrict__ phik)
{
  constexpr int LD = 72;
  __shared__ short sAh[128 * LD], sAl[128 * LD];
  __shared__ short sBh[64 * LD],  sBl[64 * LD];
  __shared__ float sPart[128][2];

  const int tid = threadIdx.x, lane = tid & 63, wv = tid >> 6;
  const int n0 = blockIdx.x * 128, h = blockIdx.y, z = blockIdx.z;
  const int colOff = z * 1024 + h * HD;

  {
    const int r = tid >> 1, half = tid & 1;
    const float* src = qk + (size_t)(n0 + r) * 2048 + colOff + half * 32;
    float ssq = 0.f;
    #pragma unroll
    for (int j4 = 0; j4 < 8; j4++) {
      float4 v = reinterpret_cast<const float4*>(src)[j4];
      ssq += v.x * v.x + v.y * v.y + v.z * v.z + v.w * v.w;
      uint2 ph, pl;
      split_pack(v, ph, pl);
      int o = r * LD + half * 32 + j4 * 4;
      *reinterpret_cast<uint2*>(&sAh[o]) = ph;
      *reinterpret_cast<uint2*>(&sAl[o]) = pl;
    }
    sPart[r][half] = ssq;
  }
  {
    const int r = tid >> 2, q4 = tid & 3;
    const float* src = omega + (size_t)r * FM + q4 * 16;
    #pragma unroll
    for (int j4 = 0; j4 < 4; j4++) {
      float4 v = reinterpret_cast<const float4*>(src)[j4];
      uint2 ph, pl;
      split_pack(v, ph, pl);
      int o = r * LD + q4 * 16 + j4 * 4;
      *reinterpret_cast<uint2*>(&sBh[o]) = ph;
      *reinterpret_cast<uint2*>(&sBl[o]) = pl;
    }
  }
  __syncthreads();

  const int waveRow = (wv >> 1) * 64, waveCol = (wv & 1) * 32;
  const int frow = lane & 15, fk = (lane >> 4) * 8;

  f32x4 acc[4][2];
  #pragma unroll
  for (int r = 0; r < 4; r++)
    #pragma unroll
    for (int c = 0; c < 2; c++) acc[r][c] = (f32x4){0.f, 0.f, 0.f, 0.f};

  #pragma unroll
  for (int ks = 0; ks < 64; ks += 32) {
    bf16x8 ah[4], al[4], bh[2], bl[2];
    #pragma unroll
    for (int r = 0; r < 4; r++) {
      int o = (waveRow + r * 16 + frow) * LD + ks + fk;
      ah[r] = *reinterpret_cast<const bf16x8*>(&sAh[o]);
      al[r] = *reinterpret_cast<const bf16x8*>(&sAl[o]);
    }
    #pragma unroll
    for (int c = 0; c < 2; c++) {
      int o = (waveCol + c * 16 + frow) * LD + ks + fk;
      bh[c] = *reinterpret_cast<const bf16x8*>(&sBh[o]);
      bl[c] = *reinterpret_cast<const bf16x8*>(&sBl[o]);
    }
    #pragma unroll
    for (int r = 0; r < 4; r++)
      #pragma unroll
      for (int c = 0; c < 2; c++) {
        acc[r][c] = __builtin_amdgcn_mfma_f32_16x16x32_bf16(ah[r], bh[c], acc[r][c], 0, 0, 0);
        acc[r][c] = __builtin_amdgcn_mfma_f32_16x16x32_bf16(ah[r], bl[c], acc[r][c], 0, 0, 0);
        acc[r][c] = __builtin_amdgcn_mfma_f32_16x16x32_bf16(al[r], bh[c], acc[r][c], 0, 0, 0);
      }
  }

  bf16* dst = z ? phik : phiq;
  #pragma unroll
  for (int r = 0; r < 4; r++)
    #pragma unroll
    for (int c = 0; c < 2; c++)
      #pragma unroll
      for (int reg = 0; reg < 4; reg++) {
        int row = waveRow + r * 16 + (lane >> 4) * 4 + reg;
        int col = waveCol + c * 16 + (lane & 15);
        float norm = 0.5f * (sPart[row][0] + sPart[row][1]);
        float v = __expf(fminf(acc[r][c][reg] - norm, 80.f)) * 0.125f;
        dst[((size_t)h * N_TOK + n0 + row) * FM + col] = __float2bfloat16(v);
      }
}

__global__ __launch_bounds__(256) void chunk_sum(
    const bf16* __restrict__ phik, const bf16* __restrict__ vf,
    float* __restrict__ ckv, float* __restrict__ ck)
{
  const int c = blockIdx.x, h = blockIdx.y;
  __shared__ float sPk[64][65];
  __shared__ float sV[64][65];
  const int tid = threadIdx.x;
  for (int t = tid; t < 4096; t += 256) {
    int j = t >> 6, e = t & 63;
    sPk[j][e] = b2f(phik[((size_t)h * N_TOK + c * CS + j) * FM + e]);
    sV[j][e]  = b2f(vf[(size_t)(c * CS + j) * DIMM + h * HD + e]);
  }
  __syncthreads();
  const int tx = tid & 15, ty = tid >> 4;
  const int m0 = ty * 4, d0 = tx * 4;
  float acc[4][4] = {};
  for (int j = 0; j < 64; j++) {
    float p[4], v[4];
    #pragma unroll
    for (int u = 0; u < 4; u++) { p[u] = sPk[j][m0 + u]; v[u] = sV[j][d0 + u]; }
    #pragma unroll
    for (int u = 0; u < 4; u++)
      #pragma unroll
      for (int w = 0; w < 4; w++) acc[u][w] += p[u] * v[w];
  }
  float* dst = ckv + ((size_t)h * NC + c) * FM * HD;
  #pragma unroll
  for (int u = 0; u < 4; u++)
    #pragma unroll
    for (int w = 0; w < 4; w++) dst[(m0 + u) * HD + d0 + w] = acc[u][w];
  if (tid < 64) {
    float s = 0.f;
    for (int j = 0; j < 64; j++) s += sPk[j][tid];
    ck[((size_t)h * NC + c) * FM + tid] = s;
  }
}

// Register-blocked exclusive prefix over chunks.
__global__ __launch_bounds__(256) void prefix_chunks(
    float* __restrict__ ckv, float* __restrict__ ck)
{
  const int h = blockIdx.x, g = blockIdx.y;
  const int cell = g * 256 + threadIdx.x;
  const size_t base = (size_t)h * NC * 4096 + cell;
  float v[NC];
  #pragma unroll
  for (int c = 0; c < NC; c++) v[c] = ckv[base + (size_t)c * 4096];
  float run = 0.f;
  #pragma unroll
  for (int c = 0; c < NC; c++) { float t = v[c]; ckv[base + (size_t)c * 4096] = run; run += t; }
  if (g == 0 && threadIdx.x < 64) {
    const size_t b2 = (size_t)h * NC * FM + threadIdx.x;
    float u[NC];
    #pragma unroll
    for (int c = 0; c < NC; c++) u[c] = ck[b2 + (size_t)c * FM];
    float r2 = 0.f;
    #pragma unroll
    for (int c = 0; c < NC; c++) { float t = u[c]; ck[b2 + (size_t)c * FM] = r2; r2 += t; }
  }
}

__global__ __launch_bounds__(256) void attn_chunk(
    const bf16* __restrict__ phiq, const bf16* __restrict__ phik,
    const bf16* __restrict__ vf, const float* __restrict__ ckv,
    const float* __restrict__ ck, bf16* __restrict__ attn_out)
{
  const int c = blockIdx.x, h = blockIdx.y;
  __shared__ float sPq[64][65];
  __shared__ float sPk[64][65];
  __shared__ float sV[64][65];
  __shared__ float sS[64][65];
  __shared__ float sKc[64];
  __shared__ float sDen[64];
  const int tid = threadIdx.x;
  const float* ckv_base = ckv + ((size_t)h * NC + c) * 4096;
  for (int t = tid; t < 4096; t += 256) {
    int i = t >> 6, e = t & 63;
    sPq[i][e] = b2f(phiq[((size_t)h * N_TOK + c * CS + i) * FM + e]);
    sPk[i][e] = b2f(phik[((size_t)h * N_TOK + c * CS + i) * FM + e]);
    sV[i][e]  = b2f(vf[(size_t)(c * CS + i) * DIMM + h * HD + e]);
    sS[i][e]  = ckv_base[t];
  }
  if (tid < 64) sKc[tid] = ck[((size_t)h * NC + c) * FM + tid];
  __syncthreads();

  const int tx = tid & 15, ty = tid >> 4;
  const int i0 = ty * 4, j0 = tx * 4;

  float accA[4][4] = {};
  for (int m = 0; m < 64; m++) {
    float a[4], b[4];
    #pragma unroll
    for (int u = 0; u < 4; u++) { a[u] = sPq[i0 + u][m]; b[u] = sPk[j0 + u][m]; }
    #pragma unroll
    for (int u = 0; u < 4; u++)
      #pragma unroll
      for (int w = 0; w < 4; w++) accA[u][w] += a[u] * b[w];
  }
  __syncthreads();
  #pragma unroll
  for (int u = 0; u < 4; u++)
    #pragma unroll
    for (int w = 0; w < 4; w++)
      sPk[i0 + u][j0 + w] = (j0 + w <= i0 + u) ? accA[u][w] : 0.f;
  __syncthreads();

  if (tid < 64) {
    float den = 0.f;
    for (int m = 0; m < 64; m++) den += sPq[tid][m] * sKc[m];
    for (int j = 0; j < 64; j++) den += sPk[tid][j];
    sDen[tid] = 1.f / (den + 1e-6f);
  }
  __syncthreads();

  float accO[4][4] = {};
  for (int j = 0; j < 64; j++) {
    float a[4], v[4];
    #pragma unroll
    for (int u = 0; u < 4; u++) { a[u] = sPk[i0 + u][j]; v[u] = sV[j][j0 + u]; }
    #pragma unroll
    for (int u = 0; u < 4; u++)
      #pragma unroll
      for (int w = 0; w < 4; w++) accO[u][w] += a[u] * v[w];
  }
  for (int m = 0; m < 64; m++) {
    float a[4], s[4];
    #pragma unroll
    for (int u = 0; u < 4; u++) { a[u] = sPq[i0 + u][m]; s[u] = sS[m][j0 + u]; }
    #pragma unroll
    for (int u = 0; u < 4; u++)
      #pragma unroll
      for (int w = 0; w < 4; w++) accO[u][w] += a[u] * s[w];
  }
  #pragma unroll
  for (int u = 0; u < 4; u++) {
    int n = c * CS + i0 + u;
    float inv = sDen[i0 + u];
    uint2 pk2;
    pk2.x = (unsigned)f2bfu(accO[u][0] * inv) | ((unsigned)f2bfu(accO[u][1] * inv) << 16);
    pk2.y = (unsigned)f2bfu(accO[u][2] * inv) | ((unsigned)f2bfu(accO[u][3] * inv) << 16);
    *reinterpret_cast<uint2*>(attn_out + (size_t)n * DIMM + h * HD + j0) = pk2;
  }
}

extern "C" void kernel_launch(void* const* d_in, const int* in_sizes, int n_in,
                              void* d_out, int out_size, void* d_ws, size_t ws_size,
                              hipStream_t stream) {
  (void)in_sizes; (void)n_in; (void)out_size; (void)ws_size;
  const float* x     = (const float*)d_in[0];
  const float* omega = (const float*)d_in[1];
  const float* wq    = (const float*)d_in[2];
  const float* wk    = (const float*)d_in[3];
  const float* wv    = (const float*)d_in[4];
  const float* wo    = (const float*)d_in[5];
  const float* bo    = (const float*)d_in[6];
  float* out = (float*)d_out;

  char* w = (char*)d_ws;
  bf16*  x_hi    = (bf16*)(w);                       // 4 MB   [later: attn bf16]
  bf16*  x_lo    = (bf16*)(w + (4u  << 20));         // 4 MB   [later: wo_bf]
  bf16*  wqkv_hi = (bf16*)(w + (8u  << 20));         // 6 MB
  bf16*  wqkv_lo = (bf16*)(w + (14u << 20));         // 6 MB
  float* qk      = (float*)(w + (20u << 20));        // 16 MB  [later: ckv+ck]
  bf16*  vbf     = (bf16*)(w + (36u << 20));         // 4 MB
  bf16*  phiq    = (bf16*)(w + (40u << 20));         // 4 MB
  bf16*  phik    = (bf16*)(w + (44u << 20));         // 4 MB
  float* ckv     = (float*)(w + (20u << 20));        // alias qk (dead after phi)
  float* ck      = (float*)(w + (28u << 20));
  bf16*  attnb   = x_hi;                             // alias (x dead after QKV GEMM)
  bf16*  wo_bf   = x_lo;                             // alias

  cvt_all<<<5120, 256, 0, stream>>>((const float4*)x, (const float4*)wq,
                                    (const float4*)wk, (const float4*)wv,
                                    x_hi, x_lo, wqkv_hi, wqkv_lo);

  gemm_split_qkv<<<dim3(24, 16), 256, 0, stream>>>(x_hi, x_lo, wqkv_hi, wqkv_lo, qk, vbf, DIMM);

  cvt_bf<<<1024, 256, 0, stream>>>((const float4*)wo, wo_bf, 262144);

  phi_mfma<<<dim3(N_TOK / 128, NH, 2), 256, 0, stream>>>(qk, omega, phiq, phik);

  chunk_sum<<<dim3(NC, NH), 256, 0, stream>>>(phik, vbf, ckv, ck);
  prefix_chunks<<<dim3(NH, 16), 256, 0, stream>>>(ckv, ck);
  attn_chunk<<<dim3(NC, NH), 256, 0, stream>>>(phiq, phik, vbf, ckv, ck, attnb);

  gemm_bf16_out<<<dim3(8, 16), 256, 0, stream>>>(attnb, wo_bf, bo, out, DIMM, DIMM);
}